// Round 6
// baseline (190.103 us; speedup 1.0000x reference)
//
#include <hip/hip_runtime.h>

// LocalSelfAttention2d  B=16,C=256,H=W=64,P=8,HEADS=8,D=32
// Round 6: kill K1's x-staging (measured ~40us + 2x HBM over-fetch).
//  K0 conv_w: w_proj/w_out -> fp16 in d_ws.
//  T  xt_transpose: x [c][h][w] fp32 -> x_t [h][w][c] fp16 (LDS-swizzled).
//  K1 lsa_qkv_attn_xt: QKV GEMM with B-frags DIRECT from global x_t
//     (no LDS staging, no phase-1, single barrier), then attention as R5.
//  K2 lsa_outproj: unchanged R5 (+unroll2).
//  Fallback: if ws_size < 64.5MB, launch the proven R5 path.
// MFMA 16x16x32_f16 layouts (R4/R5 end-to-end verified):
//   A: row=l&15, k=(l>>4)*8+v ; B: col=l&15, same k ; D: col=l&15, row=(l>>4)*4+r.

typedef _Float16 f16x8 __attribute__((ext_vector_type(8)));
typedef _Float16 f16x4 __attribute__((ext_vector_type(4)));
typedef float    f32x4 __attribute__((ext_vector_type(4)));
typedef unsigned short u16;
typedef unsigned long long u64;

#define SCALE 0.17677669529663687f  // 1/sqrt(32)
#define AWT_S 268   // (fallback) x-window [64][268]
#define QK_S  40    // Q/K [64 pix][40 d]
#define VT_S  72    // V  [32 d][72 k]
#define PB_S  40    // P-half [64 q][40 k]
#define LT_S  264   // T-kernel staging stride

__device__ __forceinline__ u16 f2hu(float f) {
    _Float16 h = (_Float16)f; return __builtin_bit_cast(u16, h);
}
__device__ __forceinline__ u64 pack4h(f32x4 v) {
    return (u64)f2hu(v[0]) | ((u64)f2hu(v[1]) << 16)
         | ((u64)f2hu(v[2]) << 32) | ((u64)f2hu(v[3]) << 48);
}
__device__ __forceinline__ f16x8 ld2x4(const u16* p) {
    f16x4 lo = *(const f16x4*)p;
    f16x4 hi = *(const f16x4*)(p + 4);
    return __builtin_shufflevector(lo, hi, 0, 1, 2, 3, 4, 5, 6, 7);
}

// ---------------- K0: weight fp32 -> fp16 ----------------
__global__ __launch_bounds__(512)
void conv_w(const float* __restrict__ wp, const float* __restrict__ wo,
            u16* __restrict__ w16, u16* __restrict__ wo16) {
    int idx = blockIdx.x * 512 + threadIdx.x;
    if (idx < 196608) w16[idx] = f2hu(wp[idx]);
    int j = idx - 196608;
    if (j >= 0 && j < 65536) wo16[j] = f2hu(wo[j]);
}

// ---------------- T: x [c][h][w] fp32 -> x_t [h][w][c] fp16 ----------------
__global__ __launch_bounds__(256)
void xt_transpose(const float* __restrict__ x, u16* __restrict__ xt) {
    __shared__ u16 Lt[64 * LT_S];   // 33792 B, swizzle c ^ (((w>>2)&7)<<3)
    const int tid = threadIdx.x;
    const int y = blockIdx.x, b = blockIdx.y;
    const float* xb = x + ((size_t)b * 256) * 4096 + y * 64;
    #pragma unroll
    for (int i = 0; i < 16; ++i) {
        int idx = tid + i * 256;            // 4096 float4s: c=idx>>4, w4=(idx&15)*4
        int c = idx >> 4, w4 = (idx & 15) << 2;
        float4 v = *(const float4*)(xb + (size_t)c * 4096 + w4);
        float vv[4] = {v.x, v.y, v.z, v.w};
        #pragma unroll
        for (int j = 0; j < 4; ++j) {
            int w = w4 + j;
            Lt[w * LT_S + (c ^ (((w >> 2) & 7) << 3))] = f2hu(vv[j]);
        }
    }
    __syncthreads();
    u16* dst = xt + (((size_t)b * 64 + y) * 64) * 256;
    #pragma unroll
    for (int i = 0; i < 8; ++i) {
        int idx = tid + i * 256;            // 2048 f16x8 stores
        int w = idx >> 5, c8 = (idx & 31) << 3;
        f16x8 v = *(const f16x8*)(&Lt[w * LT_S + (c8 ^ (((w >> 2) & 7) << 3))]);
        *(f16x8*)(dst + w * 256 + c8) = v;
    }
}

// ---------------- K1': QKV projection + windowed attention (x_t direct) ----------------
__global__ __launch_bounds__(512, 4)
void lsa_qkv_attn_xt(const u16* __restrict__ xt, const u16* __restrict__ w16,
                     const float* __restrict__ position, u16* __restrict__ Ows)
{
    __shared__ u16 U[39936];   // 79872 B
    u16* Qb  = U;                          // [4][64][40] = 10240
    u16* Kb  = U + 10240;                  // [4][64][40]
    u16* Vt  = U + 20480;                  // [4][32][72] = 9216
    u16* Pb  = U + 29696;                  // [4][64][40] = 10240 -> 39936

    const int tid = threadIdx.x;
    const int hq = blockIdx.x & 1, win = blockIdx.x >> 1, b = blockIdx.y;
    const int wy = win >> 3, wx = win & 7;
    const int w = tid >> 6, m = tid & 15, lg = (tid >> 4) & 3;

    // ---- phase 2: QKV GEMM; B-frags straight from global x_t
    f32x4 acc[3][4];
    int isv[3], hhv[3], d0v[3], rowg[3];
    {
        const u16* xw = xt + ((size_t)b * 4096 + (wy * 8) * 64 + wx * 8) * 256;
        int pofs[4];
        #pragma unroll
        for (int nt = 0; nt < 4; ++nt) {
            int p = nt * 16 + m;
            pofs[nt] = ((p >> 3) * 64 + (p & 7)) * 256;
        }
        const f32x4 z = {0.f, 0.f, 0.f, 0.f};
        #pragma unroll
        for (int i = 0; i < 3; ++i) {
            #pragma unroll
            for (int nt = 0; nt < 4; ++nt) acc[i][nt] = z;
            int lr0 = (3 * w + i) * 16;           // local row: i_s*128 + hh*32 + d
            isv[i] = lr0 >> 7; hhv[i] = (lr0 >> 5) & 3; d0v[i] = lr0 & 31;
            rowg[i] = isv[i] * 256 + (hq * 4 + hhv[i]) * 32 + d0v[i];
        }
        #pragma unroll 2
        for (int kt = 0; kt < 8; ++kt) {
            f16x8 af[3];
            #pragma unroll
            for (int i = 0; i < 3; ++i)
                af[i] = *(const f16x8*)(w16 + (size_t)(rowg[i] + m) * 256 + kt * 32 + lg * 8);
            f16x8 bf[4];
            #pragma unroll
            for (int nt = 0; nt < 4; ++nt)
                bf[nt] = *(const f16x8*)(xw + pofs[nt] + kt * 32 + lg * 8);
            #pragma unroll
            for (int i = 0; i < 3; ++i)
                #pragma unroll
                for (int nt = 0; nt < 4; ++nt)
                    acc[i][nt] = __builtin_amdgcn_mfma_f32_16x16x32_f16(af[i], bf[nt], acc[i][nt], 0, 0, 0);
        }
    }

    // ---- phase 3: scatter Q/K/V to per-head LDS (disjoint rows per wave; no pre-barrier)
    {
        #pragma unroll
        for (int i = 0; i < 3; ++i) {
            int i_s = isv[i], hh = hhv[i], d0 = d0v[i];
            #pragma unroll
            for (int nt = 0; nt < 4; ++nt) {
                int pix = nt * 16 + m;
                if (i_s < 2) {
                    u16* base = (i_s == 0) ? Qb : Kb;
                    *(u64*)(base + hh * 64 * QK_S + pix * QK_S + d0 + lg * 4) = pack4h(acc[i][nt]);
                } else {
                    #pragma unroll
                    for (int r = 0; r < 4; ++r)
                        Vt[hh * 32 * VT_S + (d0 + lg * 4 + r) * VT_S + pix] = f2hu(acc[i][nt][r]);
                }
            }
        }
    }
    __syncthreads();

    // ---- phase 4: attention; 2 waves per head (wave = (hh, q-half))
    {
        const int hh = w >> 1, qh = w & 1;
        const u16* Qh = Qb + hh * 64 * QK_S;
        const u16* Kh = Kb + hh * 64 * QK_S;
        const u16* Vh = Vt + hh * 32 * VT_S;
        u16* Ph = Pb + hh * 64 * PB_S;
        const float* posh = position + (hq * 4 + hh) * 256;

        f16x8 kf[4], qf[2];
        #pragma unroll
        for (int kt = 0; kt < 4; ++kt)
            kf[kt] = *(const f16x8*)(Kh + (kt * 16 + m) * QK_S + lg * 8);
        #pragma unroll
        for (int qi = 0; qi < 2; ++qi)
            qf[qi] = *(const f16x8*)(Qh + ((2 * qh + qi) * 16 + m) * QK_S + lg * 8);

        const f32x4 z = {0.f, 0.f, 0.f, 0.f};
        f32x4 st[4][2];
        #pragma unroll
        for (int kt = 0; kt < 4; ++kt)
            #pragma unroll
            for (int qi = 0; qi < 2; ++qi)
                st[kt][qi] = __builtin_amdgcn_mfma_f32_16x16x32_f16(kf[kt], qf[qi], z, 0, 0, 0);
        // st[kt][qi]: lane holds S[q=(2qh+qi)*16+m][k=kt*16+lg*4+r]

        float inv[2];
        #pragma unroll
        for (int qi = 0; qi < 2; ++qi) {
            int q = (2 * qh + qi) * 16 + m, qy = q >> 3, qx = q & 7;
            float mx = -1e30f;
            #pragma unroll
            for (int kt = 0; kt < 4; ++kt)
                #pragma unroll
                for (int r = 0; r < 4; ++r) {
                    int k = kt * 16 + lg * 4 + r, ky = k >> 3, kx = k & 7;
                    float t = st[kt][qi][r] * SCALE + posh[(ky - qy + 8) * 16 + (kx - qx + 8)];
                    st[kt][qi][r] = t;
                    mx = fmaxf(mx, t);
                }
            mx = fmaxf(mx, __shfl_xor(mx, 16));
            mx = fmaxf(mx, __shfl_xor(mx, 32));
            float sum = 0.f;
            #pragma unroll
            for (int kt = 0; kt < 4; ++kt)
                #pragma unroll
                for (int r = 0; r < 4; ++r) {
                    float e = __expf(st[kt][qi][r] - mx);
                    st[kt][qi][r] = e; sum += e;
                }
            sum += __shfl_xor(sum, 16);
            sum += __shfl_xor(sum, 32);
            inv[qi] = 1.f / sum;
        }

        f32x4 ot[2][2];
        ot[0][0] = z; ot[0][1] = z; ot[1][0] = z; ot[1][1] = z;
        #pragma unroll
        for (int ks = 0; ks < 2; ++ks) {
            #pragma unroll
            for (int kh = 0; kh < 2; ++kh) {
                int kt = 2 * ks + kh;
                #pragma unroll
                for (int qi = 0; qi < 2; ++qi) {
                    f32x4 pv = st[kt][qi] * inv[qi];
                    *(u64*)(Ph + ((2 * qh + qi) * 16 + m) * PB_S + kh * 16 + lg * 4) = pack4h(pv);
                }
            }
            f16x8 pf[2], vf[2];
            #pragma unroll
            for (int qi = 0; qi < 2; ++qi)
                pf[qi] = *(const f16x8*)(Ph + ((2 * qh + qi) * 16 + m) * PB_S + lg * 8);
            #pragma unroll
            for (int dt = 0; dt < 2; ++dt)
                vf[dt] = *(const f16x8*)(Vh + (dt * 16 + m) * VT_S + ks * 32 + lg * 8);
            #pragma unroll
            for (int qi = 0; qi < 2; ++qi)
                #pragma unroll
                for (int dt = 0; dt < 2; ++dt)
                    ot[qi][dt] = __builtin_amdgcn_mfma_f32_16x16x32_f16(pf[qi], vf[dt], ot[qi][dt], 0, 0, 0);
        }

        // O -> Ows [bw][p=q][c] fp16; lane: c = dt*16+m, q-rows = lg*4+r
        const size_t obase = (size_t)(b * 64 + win) * 16384;
        #pragma unroll
        for (int qi = 0; qi < 2; ++qi)
            #pragma unroll
            for (int dt = 0; dt < 2; ++dt) {
                int c = (hq * 4 + hh) * 32 + dt * 16 + m;
                #pragma unroll
                for (int r = 0; r < 4; ++r) {
                    int q = (2 * qh + qi) * 16 + lg * 4 + r;
                    Ows[obase + q * 256 + c] = f2hu(ot[qi][dt][r]);
                }
            }
    }
}

// ---------------- K1 fallback (R5-verified, with in-kernel x staging) ----------------
__global__ __launch_bounds__(512, 4)
void lsa_qkv_attn(const float* __restrict__ x, const u16* __restrict__ w16,
                  const float* __restrict__ position, u16* __restrict__ Ows)
{
    __shared__ u16 U[39936];
    u16* AWT = U;
    u16* Qb  = U;
    u16* Kb  = U + 10240;
    u16* Vt  = U + 20480;
    u16* Pb  = U + 29696;

    const int tid = threadIdx.x;
    const int win = blockIdx.x, b = blockIdx.y, hq = blockIdx.z;
    const int wy = win >> 3, wx = win & 7;
    const int w = tid >> 6, m = tid & 15, lg = (tid >> 4) & 3;

    {
        const float* xb = x + ((size_t)b * 256) * 4096 + (wy * 8) * 64 + wx * 8;
        #pragma unroll
        for (int i = 0; i < 8; ++i) {
            int idx = tid + i * 512;
            int c = idx >> 4, p4 = (idx & 15) << 2;
            int py = p4 >> 3, px = p4 & 7;
            float4 v = *(const float4*)(xb + (size_t)c * 4096 + py * 64 + px);
            AWT[(p4 + 0) * AWT_S + c] = f2hu(v.x);
            AWT[(p4 + 1) * AWT_S + c] = f2hu(v.y);
            AWT[(p4 + 2) * AWT_S + c] = f2hu(v.z);
            AWT[(p4 + 3) * AWT_S + c] = f2hu(v.w);
        }
    }
    __syncthreads();

    f32x4 acc[3][4];
    int isv[3], hhv[3], d0v[3], rowg[3];
    {
        const f32x4 z = {0.f, 0.f, 0.f, 0.f};
        #pragma unroll
        for (int i = 0; i < 3; ++i) {
            #pragma unroll
            for (int nt = 0; nt < 4; ++nt) acc[i][nt] = z;
            int lr0 = (3 * w + i) * 16;
            isv[i] = lr0 >> 7; hhv[i] = (lr0 >> 5) & 3; d0v[i] = lr0 & 31;
            rowg[i] = isv[i] * 256 + (hq * 4 + hhv[i]) * 32 + d0v[i];
        }
        for (int kt = 0; kt < 8; ++kt) {
            f16x8 af[3];
            #pragma unroll
            for (int i = 0; i < 3; ++i)
                af[i] = *(const f16x8*)(w16 + (size_t)(rowg[i] + m) * 256 + kt * 32 + lg * 8);
            f16x8 bf[4];
            #pragma unroll
            for (int nt = 0; nt < 4; ++nt)
                bf[nt] = ld2x4(AWT + (nt * 16 + m) * AWT_S + kt * 32 + lg * 8);
            #pragma unroll
            for (int i = 0; i < 3; ++i)
                #pragma unroll
                for (int nt = 0; nt < 4; ++nt)
                    acc[i][nt] = __builtin_amdgcn_mfma_f32_16x16x32_f16(af[i], bf[nt], acc[i][nt], 0, 0, 0);
        }
    }
    __syncthreads();

    {
        #pragma unroll
        for (int i = 0; i < 3; ++i) {
            int i_s = isv[i], hh = hhv[i], d0 = d0v[i];
            #pragma unroll
            for (int nt = 0; nt < 4; ++nt) {
                int pix = nt * 16 + m;
                if (i_s < 2) {
                    u16* base = (i_s == 0) ? Qb : Kb;
                    *(u64*)(base + hh * 64 * QK_S + pix * QK_S + d0 + lg * 4) = pack4h(acc[i][nt]);
                } else {
                    #pragma unroll
                    for (int r = 0; r < 4; ++r)
                        Vt[hh * 32 * VT_S + (d0 + lg * 4 + r) * VT_S + pix] = f2hu(acc[i][nt][r]);
                }
            }
        }
    }
    __syncthreads();

    {
        const int hh = w >> 1, qh = w & 1;
        const u16* Qh = Qb + hh * 64 * QK_S;
        const u16* Kh = Kb + hh * 64 * QK_S;
        const u16* Vh = Vt + hh * 32 * VT_S;
        u16* Ph = Pb + hh * 64 * PB_S;
        const float* posh = position + (hq * 4 + hh) * 256;

        f16x8 kf[4], qf[2];
        #pragma unroll
        for (int kt = 0; kt < 4; ++kt)
            kf[kt] = *(const f16x8*)(Kh + (kt * 16 + m) * QK_S + lg * 8);
        #pragma unroll
        for (int qi = 0; qi < 2; ++qi)
            qf[qi] = *(const f16x8*)(Qh + ((2 * qh + qi) * 16 + m) * QK_S + lg * 8);

        const f32x4 z = {0.f, 0.f, 0.f, 0.f};
        f32x4 st[4][2];
        #pragma unroll
        for (int kt = 0; kt < 4; ++kt)
            #pragma unroll
            for (int qi = 0; qi < 2; ++qi)
                st[kt][qi] = __builtin_amdgcn_mfma_f32_16x16x32_f16(kf[kt], qf[qi], z, 0, 0, 0);

        float inv[2];
        #pragma unroll
        for (int qi = 0; qi < 2; ++qi) {
            int q = (2 * qh + qi) * 16 + m, qy = q >> 3, qx = q & 7;
            float mx = -1e30f;
            #pragma unroll
            for (int kt = 0; kt < 4; ++kt)
                #pragma unroll
                for (int r = 0; r < 4; ++r) {
                    int k = kt * 16 + lg * 4 + r, ky = k >> 3, kx = k & 7;
                    float t = st[kt][qi][r] * SCALE + posh[(ky - qy + 8) * 16 + (kx - qx + 8)];
                    st[kt][qi][r] = t;
                    mx = fmaxf(mx, t);
                }
            mx = fmaxf(mx, __shfl_xor(mx, 16));
            mx = fmaxf(mx, __shfl_xor(mx, 32));
            float sum = 0.f;
            #pragma unroll
            for (int kt = 0; kt < 4; ++kt)
                #pragma unroll
                for (int r = 0; r < 4; ++r) {
                    float e = __expf(st[kt][qi][r] - mx);
                    st[kt][qi][r] = e; sum += e;
                }
            sum += __shfl_xor(sum, 16);
            sum += __shfl_xor(sum, 32);
            inv[qi] = 1.f / sum;
        }

        f32x4 ot[2][2];
        ot[0][0] = z; ot[0][1] = z; ot[1][0] = z; ot[1][1] = z;
        #pragma unroll
        for (int ks = 0; ks < 2; ++ks) {
            #pragma unroll
            for (int kh = 0; kh < 2; ++kh) {
                int kt = 2 * ks + kh;
                #pragma unroll
                for (int qi = 0; qi < 2; ++qi) {
                    f32x4 pv = st[kt][qi] * inv[qi];
                    *(u64*)(Ph + ((2 * qh + qi) * 16 + m) * PB_S + kh * 16 + lg * 4) = pack4h(pv);
                }
            }
            f16x8 pf[2], vf[2];
            #pragma unroll
            for (int qi = 0; qi < 2; ++qi)
                pf[qi] = *(const f16x8*)(Ph + ((2 * qh + qi) * 16 + m) * PB_S + lg * 8);
            #pragma unroll
            for (int dt = 0; dt < 2; ++dt)
                vf[dt] = *(const f16x8*)(Vh + (dt * 16 + m) * VT_S + ks * 32 + lg * 8);
            #pragma unroll
            for (int qi = 0; qi < 2; ++qi)
                #pragma unroll
                for (int dt = 0; dt < 2; ++dt)
                    ot[qi][dt] = __builtin_amdgcn_mfma_f32_16x16x32_f16(pf[qi], vf[dt], ot[qi][dt], 0, 0, 0);
        }

        const size_t obase = (size_t)(b * 64 + win) * 16384;
        #pragma unroll
        for (int qi = 0; qi < 2; ++qi)
            #pragma unroll
            for (int dt = 0; dt < 2; ++dt) {
                int c = (hq * 4 + hh) * 32 + dt * 16 + m;
                #pragma unroll
                for (int r = 0; r < 4; ++r) {
                    int q = (2 * qh + qi) * 16 + lg * 4 + r;
                    Ows[obase + q * 256 + c] = f2hu(ot[qi][dt][r]);
                }
            }
    }
}

// ---------------- K2: out-projection (zero LDS) ----------------
__global__ __launch_bounds__(512, 4)
void lsa_outproj(const u16* __restrict__ Ows, const u16* __restrict__ wo16,
                 const float* __restrict__ b_out, float* __restrict__ out)
{
    const int tid = threadIdx.x;
    const int win = blockIdx.x, b = blockIdx.y;
    const int wy = win >> 3, wx = win & 7;
    const int w = tid >> 6, m = tid & 15, lg = (tid >> 4) & 3;
    const u16* Ow = Ows + (size_t)(b * 64 + win) * 16384;   // [64 p][256 c]

    f32x4 oa[2][4];
    {
        const f32x4 z = {0.f, 0.f, 0.f, 0.f};
        #pragma unroll
        for (int mt = 0; mt < 2; ++mt)
            #pragma unroll
            for (int nt = 0; nt < 4; ++nt) oa[mt][nt] = z;
    }
    #pragma unroll 2
    for (int kt = 0; kt < 8; ++kt) {
        f16x8 wf[2];
        #pragma unroll
        for (int mt = 0; mt < 2; ++mt)
            wf[mt] = *(const f16x8*)(wo16 + (size_t)(w * 32 + mt * 16 + m) * 256 + kt * 32 + lg * 8);
        f16x8 of[4];
        #pragma unroll
        for (int nt = 0; nt < 4; ++nt)
            of[nt] = *(const f16x8*)(Ow + (nt * 16 + m) * 256 + kt * 32 + lg * 8);
        #pragma unroll
        for (int mt = 0; mt < 2; ++mt)
            #pragma unroll
            for (int nt = 0; nt < 4; ++nt)
                oa[mt][nt] = __builtin_amdgcn_mfma_f32_16x16x32_f16(wf[mt], of[nt], oa[mt][nt], 0, 0, 0);
    }
    float* ob = out + ((size_t)b * 256) * 4096 + (wy * 8) * 64 + wx * 8;
    #pragma unroll
    for (int mt = 0; mt < 2; ++mt)
        #pragma unroll
        for (int nt = 0; nt < 4; ++nt) {
            int p = nt * 16 + m, py = p >> 3, px = p & 7;
            #pragma unroll
            for (int r = 0; r < 4; ++r) {
                int oc = w * 32 + mt * 16 + lg * 4 + r;
                ob[(size_t)oc * 4096 + py * 64 + px] = oa[mt][nt][r] + b_out[oc];
            }
        }
}

extern "C" void kernel_launch(void* const* d_in, const int* in_sizes, int n_in,
                              void* d_out, int out_size, void* d_ws, size_t ws_size,
                              hipStream_t stream) {
    const float* x      = (const float*)d_in[0];
    const float* w_proj = (const float*)d_in[1];
    const float* pos    = (const float*)d_in[2];
    const float* w_out  = (const float*)d_in[3];
    const float* b_out  = (const float*)d_in[4];
    float* out = (float*)d_out;

    const size_t NEED_NEW = 33554432ull + 393216 + 131072 + 33554432ull;  // ~64.5 MB
    if (ws_size >= NEED_NEW) {
        // d_ws: [0,32M) x_t fp16 [h][w][c] ; +32M w16 ; +384K wo16 ; then Ows
        u16* xt   = (u16*)d_ws;
        u16* w16  = (u16*)((char*)d_ws + 33554432);
        u16* wo16 = (u16*)((char*)d_ws + 33554432 + 393216);
        u16* Ows  = (u16*)((char*)d_ws + 33554432 + 393216 + 131072);
        conv_w<<<512, 512, 0, stream>>>(w_proj, w_out, w16, wo16);
        xt_transpose<<<dim3(64, 16), 256, 0, stream>>>(x, xt);
        lsa_qkv_attn_xt<<<dim3(128, 16), 512, 0, stream>>>(xt, w16, pos, Ows);
        lsa_outproj<<<dim3(64, 16), 512, 0, stream>>>(Ows, wo16, b_out, out);
    } else {
        // R5 fallback: Ows at 0, weights after
        u16* Ows  = (u16*)d_ws;
        u16* w16  = (u16*)((char*)d_ws + 33554432);
        u16* wo16 = (u16*)((char*)d_ws + 33947648);
        conv_w<<<512, 512, 0, stream>>>(w_proj, w_out, w16, wo16);
        lsa_qkv_attn<<<dim3(64, 16, 2), 512, 0, stream>>>(x, w16, pos, Ows);
        lsa_outproj<<<dim3(64, 16), 512, 0, stream>>>(Ows, wo16, b_out, out);
    }
}